// Round 1
// baseline (74.041 us; speedup 1.0000x reference)
//
#include <hip/hip_runtime.h>
#include <hip/hip_bf16.h>

#define M_DIM 8192
#define N_DIM 8192
#define K_DIM 64

typedef short short8 __attribute__((ext_vector_type(8)));
typedef float f32x4 __attribute__((ext_vector_type(4)));

static __device__ __forceinline__ short f2bf(float f) {
    __hip_bfloat16 h = __float2bfloat16(f);   // RNE convert
    union { __hip_bfloat16 h; short s; } u;
    u.h = h;
    return u.s;
}

// Kernel 1: activation [64, 8192] f32 -> actT [8192, 64] bf16 (transposed, packed)
__global__ __launch_bounds__(256) void transpose_act(const float* __restrict__ act,
                                                     short* __restrict__ actT) {
    __shared__ float tile[64][65];   // +1 pad: conflict-free column reads
    const int n0 = blockIdx.x * 64;
    const int tid = threadIdx.x;
    #pragma unroll
    for (int i = tid; i < 64 * 64; i += 256) {
        int k = i >> 6, n = i & 63;
        tile[k][n] = act[k * N_DIM + n0 + n];     // coalesced row reads
    }
    __syncthreads();
    #pragma unroll
    for (int i = tid; i < 64 * 64; i += 256) {
        int n = i >> 6, k = i & 63;
        actT[(n0 + n) * 64 + k] = f2bf(tile[k][n]);  // coalesced bf16 writes
    }
}

// Kernel 2: C[m,n] = sum_k dq[m,k] * act[k,n]
// Block: 256 threads = 4 waves (2x2), tile 128x128, full K=64, no LDS.
__global__ __launch_bounds__(256) void gemm_dq(const float* __restrict__ scale,
                                               const int* __restrict__ offset,
                                               const int* __restrict__ weight,
                                               const short* __restrict__ actT,
                                               float* __restrict__ C) {
    const int tid  = threadIdx.x;
    const int lane = tid & 63;
    const int wid  = tid >> 6;
    const int l15  = lane & 15;
    const int l4   = lane >> 4;

    const int tiles_n = N_DIM / 128;             // 64
    const int bm = blockIdx.x / tiles_n;
    const int bn = blockIdx.x % tiles_n;
    const int m0 = bm * 128 + (wid >> 1) * 64;   // wave's 64x64 subtile origin
    const int n0 = bn * 128 + (wid & 1) * 64;

    // ---- A fragments: dequantize 4-bit weights directly into registers.
    // Lane holds rows m = m0+fm*16+(lane&15), k = kh*32 + (lane>>4)*8 + j
    // => exactly group g = kh*4 + (lane>>4): one weight word, one scale, one offset nibble.
    short8 afrag[2][4];
    #pragma unroll
    for (int kh = 0; kh < 2; ++kh) {
        const int g = kh * 4 + l4;
        #pragma unroll
        for (int fm = 0; fm < 4; ++fm) {
            const int m = m0 + fm * 16 + l15;
            const unsigned w = (unsigned)weight[m * 8 + g];
            const float   s = scale[m * 8 + g];
            const int   off = (int)(((unsigned)offset[m] >> (4 * g)) & 15u);
            short8 a;
            #pragma unroll
            for (int j = 0; j < 8; ++j) {
                const int wv = (int)((w >> (4 * j)) & 15u);
                a[j] = f2bf(s * (float)(wv - off));   // matches ref: scale*(w-off), f32
            }
            afrag[kh][fm] = a;
        }
    }

    // ---- B fragments: 16B loads from pre-transposed bf16 activation (L2-hot).
    short8 bfrag[2][4];
    #pragma unroll
    for (int kh = 0; kh < 2; ++kh) {
        #pragma unroll
        for (int fn = 0; fn < 4; ++fn) {
            const int n = n0 + fn * 16 + l15;
            bfrag[kh][fn] = *reinterpret_cast<const short8*>(actT + n * 64 + kh * 32 + l4 * 8);
        }
    }

    // ---- MFMA: 4x4 fragments x 2 k-halves = 32 mfma ops
    f32x4 acc[4][4] = {};
    #pragma unroll
    for (int fm = 0; fm < 4; ++fm) {
        #pragma unroll
        for (int fn = 0; fn < 4; ++fn) {
            acc[fm][fn] = __builtin_amdgcn_mfma_f32_16x16x32_bf16(
                afrag[0][fm], bfrag[0][fn], acc[fm][fn], 0, 0, 0);
            acc[fm][fn] = __builtin_amdgcn_mfma_f32_16x16x32_bf16(
                afrag[1][fm], bfrag[1][fn], acc[fm][fn], 0, 0, 0);
        }
    }

    // ---- Store: C/D layout col = lane&15, row = (lane>>4)*4 + j  [m89-verified]
    #pragma unroll
    for (int fm = 0; fm < 4; ++fm) {
        const int mrow = m0 + fm * 16 + l4 * 4;
        #pragma unroll
        for (int fn = 0; fn < 4; ++fn) {
            const int ncol = n0 + fn * 16 + l15;
            #pragma unroll
            for (int j = 0; j < 4; ++j) {
                C[(size_t)(mrow + j) * N_DIM + ncol] = acc[fm][fn][j];
            }
        }
    }
}

extern "C" void kernel_launch(void* const* d_in, const int* in_sizes, int n_in,
                              void* d_out, int out_size, void* d_ws, size_t ws_size,
                              hipStream_t stream) {
    const float* scale  = (const float*)d_in[0];
    const int*   offset = (const int*)d_in[1];
    const int*   weight = (const int*)d_in[2];
    const float* act    = (const float*)d_in[3];
    float* out  = (float*)d_out;
    short* actT = (short*)d_ws;   // 8192*64*2 = 1 MB scratch

    transpose_act<<<N_DIM / 64, 256, 0, stream>>>(act, actT);

    const int grid = (M_DIM / 128) * (N_DIM / 128);   // 4096 blocks
    gemm_dq<<<grid, 256, 0, stream>>>(scale, offset, weight, actT, out);
}

// Round 2
// 70.644 us; speedup vs baseline: 1.0481x; 1.0481x over previous
//
#include <hip/hip_runtime.h>
#include <hip/hip_bf16.h>

#define M_DIM 8192
#define N_DIM 8192
#define K_DIM 64

typedef short short8 __attribute__((ext_vector_type(8)));
typedef float f32x4 __attribute__((ext_vector_type(4)));

static __device__ __forceinline__ short f2bf(float f) {
    __hip_bfloat16 h = __float2bfloat16(f);   // RNE convert
    union { __hip_bfloat16 h; short s; } u;
    u.h = h;
    return u.s;
}

// Kernel 1: activation [64, 8192] f32 -> actT [8192, 64] bf16 (transposed, packed)
__global__ __launch_bounds__(256) void transpose_act(const float* __restrict__ act,
                                                     short* __restrict__ actT) {
    __shared__ float tile[64][65];   // +1 pad: conflict-free column reads
    const int n0 = blockIdx.x * 64;
    const int tid = threadIdx.x;
    #pragma unroll
    for (int i = tid; i < 64 * 64; i += 256) {
        int k = i >> 6, n = i & 63;
        tile[k][n] = act[k * N_DIM + n0 + n];     // coalesced row reads
    }
    __syncthreads();
    #pragma unroll
    for (int i = tid; i < 64 * 64; i += 256) {
        int n = i >> 6, k = i & 63;
        actT[(n0 + n) * 64 + k] = f2bf(tile[k][n]);  // coalesced bf16 writes
    }
}

// Kernel 2: C[m,n] = sum_k dq[m,k] * act[k,n]
// Block: 256 threads = 4 waves (2x2), tile 128x128, full K=64.
// Epilogue: per-wave LDS staging (no barriers) -> fully coalesced dwordx4 stores.
__global__ __launch_bounds__(256) void gemm_dq(const float* __restrict__ scale,
                                               const int* __restrict__ offset,
                                               const int* __restrict__ weight,
                                               const short* __restrict__ actT,
                                               float* __restrict__ C) {
    // wave-private staging: 64 rows x 32 cols f32 = 8 KB per wave, 32 KB per block
    __shared__ float cs[4][64 * 32];

    const int tid  = threadIdx.x;
    const int lane = tid & 63;
    const int wid  = tid >> 6;
    const int l15  = lane & 15;
    const int l4   = lane >> 4;

    const int tiles_n = N_DIM / 128;             // 64
    const int bm = blockIdx.x / tiles_n;
    const int bn = blockIdx.x % tiles_n;
    const int m0 = bm * 128 + (wid >> 1) * 64;   // wave's 64x64 subtile origin
    const int n0 = bn * 128 + (wid & 1) * 64;

    // ---- A fragments: dequantize 4-bit weights directly into registers.
    // Lane holds rows m = m0+fm*16+(lane&15), k = kh*32 + (lane>>4)*8 + j
    // => exactly group g = kh*4 + (lane>>4): one weight word, one scale, one offset nibble.
    short8 afrag[2][4];
    #pragma unroll
    for (int kh = 0; kh < 2; ++kh) {
        const int g = kh * 4 + l4;
        #pragma unroll
        for (int fm = 0; fm < 4; ++fm) {
            const int m = m0 + fm * 16 + l15;
            const unsigned w = (unsigned)weight[m * 8 + g];
            const float   s = scale[m * 8 + g];
            const int   off = (int)(((unsigned)offset[m] >> (4 * g)) & 15u);
            short8 a;
            #pragma unroll
            for (int j = 0; j < 8; ++j) {
                const int wv = (int)((w >> (4 * j)) & 15u);
                a[j] = f2bf(s * (float)(wv - off));   // matches ref: scale*(w-off), f32
            }
            afrag[kh][fm] = a;
        }
    }

    // ---- B fragments: 16B loads from pre-transposed bf16 activation (L2-hot).
    short8 bfrag[2][4];
    #pragma unroll
    for (int kh = 0; kh < 2; ++kh) {
        #pragma unroll
        for (int fn = 0; fn < 4; ++fn) {
            const int n = n0 + fn * 16 + l15;
            bfrag[kh][fn] = *reinterpret_cast<const short8*>(actT + n * 64 + kh * 32 + l4 * 8);
        }
    }

    // ---- MFMA: 4x4 fragments x 2 k-halves = 32 mfma ops
    f32x4 acc[4][4] = {};
    #pragma unroll
    for (int fm = 0; fm < 4; ++fm) {
        #pragma unroll
        for (int fn = 0; fn < 4; ++fn) {
            acc[fm][fn] = __builtin_amdgcn_mfma_f32_16x16x32_bf16(
                afrag[0][fm], bfrag[0][fn], acc[fm][fn], 0, 0, 0);
            acc[fm][fn] = __builtin_amdgcn_mfma_f32_16x16x32_bf16(
                afrag[1][fm], bfrag[1][fn], acc[fm][fn], 0, 0, 0);
        }
    }

    // ---- Epilogue: stage per-wave 64x32 halves in LDS with XOR swizzle,
    //      then fully-coalesced float4 stores (8 full 128B lines per wave instr).
    float* ws = &cs[wid][0];
    #pragma unroll
    for (int pass = 0; pass < 2; ++pass) {
        // scatter accumulator into LDS (2-way bank conflict = free)
        #pragma unroll
        for (int fm = 0; fm < 4; ++fm) {
            #pragma unroll
            for (int fl = 0; fl < 2; ++fl) {
                const int fn  = pass * 2 + fl;
                const int col = fl * 16 + l15;
                #pragma unroll
                for (int j = 0; j < 4; ++j) {
                    const int row = fm * 16 + l4 * 4 + j;
                    const int swz = ((((col >> 2) ^ (row & 7)) << 2) | (col & 3));
                    ws[row * 32 + swz] = acc[fm][fn][j];
                }
            }
        }
        // wave-internal RAW on LDS: ds ops are in-order per wave; ensure data visible
        asm volatile("s_waitcnt lgkmcnt(0)" ::: "memory");
        // vectorized read-back + store: lane covers one float4; 8 lanes = one row (128B line)
        #pragma unroll
        for (int r = 0; r < 8; ++r) {
            const int row = r * 8 + (lane >> 3);
            const int cb  = lane & 7;
            const f32x4 v = *reinterpret_cast<const f32x4*>(
                &ws[row * 32 + ((cb ^ (row & 7)) << 2)]);
            const size_t gr = (size_t)(m0 + row);
            const size_t gc = (size_t)(n0 + pass * 32 + cb * 4);
            *reinterpret_cast<f32x4*>(&C[gr * N_DIM + gc]) = v;
        }
    }
}

extern "C" void kernel_launch(void* const* d_in, const int* in_sizes, int n_in,
                              void* d_out, int out_size, void* d_ws, size_t ws_size,
                              hipStream_t stream) {
    const float* scale  = (const float*)d_in[0];
    const int*   offset = (const int*)d_in[1];
    const int*   weight = (const int*)d_in[2];
    const float* act    = (const float*)d_in[3];
    float* out  = (float*)d_out;
    short* actT = (short*)d_ws;   // 8192*64*2 = 1 MB scratch

    transpose_act<<<N_DIM / 64, 256, 0, stream>>>(act, actT);

    const int grid = (M_DIM / 128) * (N_DIM / 128);   // 4096 blocks
    gemm_dq<<<grid, 256, 0, stream>>>(scale, offset, weight, actT, out);
}